// Round 12
// baseline (1735.996 us; speedup 1.0000x reference)
//
#include <hip/hip_runtime.h>

#define S_LEN 1024
#define B_DIM 64
#define H_DIM 512
#define Y_SZ ((size_t)S_LEN * B_DIM * H_DIM)   // 33,554,432 elements

// ---------------------------------------------------------------------------
// GEMM: C[m,n] = sum_k A[m,k]*W[n,k] + bias[n]. Pure VALU fp32 (MFMA is
// unusable on this harness toolchain, r6-r10). Same staging + barrier
// structure as the r5/r11-proven kernel; ONLY the inner read/compute pattern
// changed: thread tile 4x16 -> 8x8 with wave-broadcast b128 A reads and
// conflict-free b128 B reads, halving LDS instructions per FMA (LDS pipe was
// the r11 bottleneck: VALUBusy 55%, 128 LDS instr / 1024 FMA / kt).
// Block owns 64 rows exclusively; all C stores deferred to the epilogue after
// the last staging barrier -> in-place safe (C may alias A).
// Thread map: tr = tid>>6 (wave id, rows tr*8..+8 -> A reads broadcast across
// the whole wave); tc = tid&63 (cols tc*4..+4 and 256+tc*4..+4).
// ---------------------------------------------------------------------------
__global__ __launch_bounds__(512) void gemm_valu(
    const float* A, const float* __restrict__ W,
    const float* __restrict__ bias, float* C) {
  __shared__ float Bl[16][512];  // [k][n], staged transposed
  __shared__ float Al[64][16];   // [r][k]

  const int tid = threadIdx.x;
  const int tr = tid >> 6;   // 0..7 : rows tr*8..tr*8+8 (uniform per wave)
  const int tc = tid & 63;   // 0..63: cols tc*4, 256+tc*4
  const int brow = blockIdx.x * 64;

  float acc[8][8];
#pragma unroll
  for (int i = 0; i < 8; ++i)
#pragma unroll
    for (int j = 0; j < 8; ++j) acc[i][j] = 0.0f;

  for (int kt = 0; kt < 32; ++kt) {
    // --- stage B transposed (unchanged from r5): W row tid, k-chunk kt*16
    {
      const float* wp = W + (size_t)tid * 512 + kt * 16;
      float4 w0 = *(const float4*)(wp + 0);
      float4 w1 = *(const float4*)(wp + 4);
      float4 w2 = *(const float4*)(wp + 8);
      float4 w3 = *(const float4*)(wp + 12);
      Bl[0][tid] = w0.x;  Bl[1][tid] = w0.y;  Bl[2][tid] = w0.z;  Bl[3][tid] = w0.w;
      Bl[4][tid] = w1.x;  Bl[5][tid] = w1.y;  Bl[6][tid] = w1.z;  Bl[7][tid] = w1.w;
      Bl[8][tid] = w2.x;  Bl[9][tid] = w2.y;  Bl[10][tid] = w2.z; Bl[11][tid] = w2.w;
      Bl[12][tid] = w3.x; Bl[13][tid] = w3.y; Bl[14][tid] = w3.z; Bl[15][tid] = w3.w;
    }
    // --- stage A (unchanged): r = tid>>3, kk = (tid&7)*2
    {
      const int r = tid >> 3, kk = (tid & 7) * 2;
      const float* ap = A + (size_t)(brow + r) * 512 + kt * 16 + kk;
      Al[r][kk] = ap[0];
      Al[r][kk + 1] = ap[1];
    }
    __syncthreads();
    // --- compute: 4 k-groups of 4; A rows as broadcast float4 along k
#pragma unroll
    for (int kq = 0; kq < 4; ++kq) {
      float4 a[8];
#pragma unroll
      for (int i = 0; i < 8; ++i)
        a[i] = *(const float4*)&Al[tr * 8 + i][kq * 4];  // wave-broadcast 16B
#pragma unroll
      for (int kk = 0; kk < 4; ++kk) {
        const int k = kq * 4 + kk;
        float4 b0 = *(const float4*)&Bl[k][tc * 4];        // contiguous 16B/lane
        float4 b1 = *(const float4*)&Bl[k][256 + tc * 4];
#pragma unroll
        for (int i = 0; i < 8; ++i) {
          const float av = (kk == 0) ? a[i].x : (kk == 1) ? a[i].y
                         : (kk == 2) ? a[i].z : a[i].w;
          acc[i][0] += av * b0.x; acc[i][1] += av * b0.y;
          acc[i][2] += av * b0.z; acc[i][3] += av * b0.w;
          acc[i][4] += av * b1.x; acc[i][5] += av * b1.y;
          acc[i][6] += av * b1.z; acc[i][7] += av * b1.w;
        }
      }
    }
    __syncthreads();
  }

  // Epilogue: all staging (A) reads complete block-wide -> safe to write C.
#pragma unroll
  for (int i = 0; i < 8; ++i) {
    const int row = brow + tr * 8 + i;
    const int c0 = tc * 4;
    float4 o0, o1;
    o0.x = acc[i][0] + bias[c0 + 0];
    o0.y = acc[i][1] + bias[c0 + 1];
    o0.z = acc[i][2] + bias[c0 + 2];
    o0.w = acc[i][3] + bias[c0 + 3];
    o1.x = acc[i][4] + bias[256 + c0 + 0];
    o1.y = acc[i][5] + bias[256 + c0 + 1];
    o1.z = acc[i][6] + bias[256 + c0 + 2];
    o1.w = acc[i][7] + bias[256 + c0 + 3];
    *(float4*)&C[(size_t)row * 512 + c0] = o0;
    *(float4*)&C[(size_t)row * 512 + 256 + c0] = o1;
  }
}

// ---------------------------------------------------------------------------
// Scan with PREFETCH DEPTH 8 (r11's depth-4 cut scan 545->~350 µs; residual
// latency still exposed -> deepen the ring). One wave per batch row; h in
// fp32 regs; LN via dual shfl_xor butterfly; relu6; statically-indexed ring
// (k compile-time after unroll, rule #20). In-place safe: lin[s+8] read 8
// steps before y[s+8] written; thread-private 8-elem chunks.
// ---------------------------------------------------------------------------
__global__ __launch_bounds__(64) void scan_ln_relu6(
    const float* lin, const float* __restrict__ rec,
    const float* __restrict__ gam, const float* __restrict__ bet,
    float* y, float* __restrict__ hlast) {
  const int b = blockIdx.x;
  const int lane = threadIdx.x;
  const int e0 = lane * 8;

  float rf[8], gf[8], bp[8], h[8];
#pragma unroll
  for (int i = 0; i < 8; ++i) {
    rf[i] = rec[e0 + i];
    gf[i] = gam[e0 + i];
    bp[i] = bet[e0 + i];
    h[i] = 0.0f;
  }

  const size_t BH = (size_t)B_DIM * H_DIM;
  const size_t base = (size_t)b * H_DIM + e0;

  float4 pa[8], pb[8];  // prefetch ring: row s0+k held in pa[k]/pb[k]
#pragma unroll
  for (int k = 0; k < 8; ++k) {
    pa[k] = *(const float4*)&lin[base + (size_t)k * BH];
    pb[k] = *(const float4*)&lin[base + (size_t)k * BH + 4];
  }

  for (int s0 = 0; s0 < S_LEN; s0 += 8) {
#pragma unroll
    for (int k = 0; k < 8; ++k) {   // k compile-time after unroll
      const int s = s0 + k;
      float hv[8];
      hv[0] = pa[k].x + rf[0] * h[0]; hv[1] = pa[k].y + rf[1] * h[1];
      hv[2] = pa[k].z + rf[2] * h[2]; hv[3] = pa[k].w + rf[3] * h[3];
      hv[4] = pb[k].x + rf[4] * h[4]; hv[5] = pb[k].y + rf[5] * h[5];
      hv[6] = pb[k].z + rf[6] * h[6]; hv[7] = pb[k].w + rf[7] * h[7];
      if (s + 8 < S_LEN) {  // issue prefetch for s+8 (consumed 8 steps later)
        pa[k] = *(const float4*)&lin[base + (size_t)(s + 8) * BH];
        pb[k] = *(const float4*)&lin[base + (size_t)(s + 8) * BH + 4];
      }
      float s1 = 0.0f, s2 = 0.0f;
#pragma unroll
      for (int i = 0; i < 8; ++i) {
        s1 += hv[i];
        s2 += hv[i] * hv[i];
      }
#pragma unroll
      for (int off = 32; off >= 1; off >>= 1) {
        s1 += __shfl_xor(s1, off);
        s2 += __shfl_xor(s2, off);
      }
      const float mu = s1 * (1.0f / 512.0f);
      const float var = s2 * (1.0f / 512.0f) - mu * mu;  // biased variance
      const float rs = rsqrtf(var + 1e-6f);
      float4 o0, o1;
      float v;
      v = (hv[0] - mu) * rs * gf[0] + bp[0]; v = fminf(fmaxf(v, 0.0f), 6.0f); h[0] = v; o0.x = v;
      v = (hv[1] - mu) * rs * gf[1] + bp[1]; v = fminf(fmaxf(v, 0.0f), 6.0f); h[1] = v; o0.y = v;
      v = (hv[2] - mu) * rs * gf[2] + bp[2]; v = fminf(fmaxf(v, 0.0f), 6.0f); h[2] = v; o0.z = v;
      v = (hv[3] - mu) * rs * gf[3] + bp[3]; v = fminf(fmaxf(v, 0.0f), 6.0f); h[3] = v; o0.w = v;
      v = (hv[4] - mu) * rs * gf[4] + bp[4]; v = fminf(fmaxf(v, 0.0f), 6.0f); h[4] = v; o1.x = v;
      v = (hv[5] - mu) * rs * gf[5] + bp[5]; v = fminf(fmaxf(v, 0.0f), 6.0f); h[5] = v; o1.y = v;
      v = (hv[6] - mu) * rs * gf[6] + bp[6]; v = fminf(fmaxf(v, 0.0f), 6.0f); h[6] = v; o1.z = v;
      v = (hv[7] - mu) * rs * gf[7] + bp[7]; v = fminf(fmaxf(v, 0.0f), 6.0f); h[7] = v; o1.w = v;
      float* yp = y + base + (size_t)s * BH;
      *(float4*)yp = o0;
      *(float4*)(yp + 4) = o1;
    }
  }

  float* hp = hlast + b * 1024 + e0;
  float4 h0; h0.x = h[0]; h0.y = h[1]; h0.z = h[2]; h0.w = h[3];
  float4 h1; h1.x = h[4]; h1.y = h[5]; h1.z = h[6]; h1.w = h[7];
  *(float4*)hp = h0;
  *(float4*)(hp + 4) = h1;
}

extern "C" void kernel_launch(void* const* d_in, const int* in_sizes, int n_in,
                              void* d_out, int out_size, void* d_ws, size_t ws_size,
                              hipStream_t stream) {
  const float* x   = (const float*)d_in[0];
  const float* W0  = (const float*)d_in[1];
  const float* b0  = (const float*)d_in[2];
  const float* r0  = (const float*)d_in[3];
  const float* g0  = (const float*)d_in[4];
  const float* be0 = (const float*)d_in[5];
  const float* W1  = (const float*)d_in[6];
  const float* b1  = (const float*)d_in[7];
  const float* r1  = (const float*)d_in[8];
  const float* g1  = (const float*)d_in[9];
  const float* be1 = (const float*)d_in[10];

  float* out = (float*)d_out;
  float* R   = out;              // y-region: lin0 -> y0 -> lin1 -> y, in place
  float* hl0 = out + Y_SZ;       // hiddens flat: out[Y_SZ + b*1024 + l*512 + h]
  float* hl1 = out + Y_SZ + 512;
  (void)d_ws; (void)ws_size; (void)in_sizes; (void)n_in; (void)out_size;

  // layer 0
  gemm_valu<<<1024, 512, 0, stream>>>(x, W0, b0, R);
  scan_ln_relu6<<<64, 64, 0, stream>>>(R, r0, g0, be0, R, hl0);
  // layer 1 (reads y0 from R, writes lin1 over R; in-place-safe by design)
  gemm_valu<<<1024, 512, 0, stream>>>(R, W1, b1, R);
  scan_ln_relu6<<<64, 64, 0, stream>>>(R, r1, g1, be1, R, hl1);
}

// Round 13
// 1662.549 us; speedup vs baseline: 1.0442x; 1.0442x over previous
//
#include <hip/hip_runtime.h>

#define S_LEN 1024
#define B_DIM 64
#define H_DIM 512
#define Y_SZ ((size_t)S_LEN * B_DIM * H_DIM)   // 33,554,432 elements

// ---------------------------------------------------------------------------
// GEMM (r11 EXACT, hardware-proven 492 µs): C[m,n] = sum_k A[m,k]*W[n,k] +
// bias[n]. Pure VALU fp32. Block owns 64 rows exclusively; all C stores
// deferred past the last staging barrier -> in-place safe (C may alias A).
// CRITICAL: this kernel compiles to exactly 64 VGPR -> 8 waves/SIMD. The
// r12 8x8-tile variant hit 68 VGPR -> occupancy halved (m69 cliff) -> 570 µs.
// Do not add register pressure here.
// ---------------------------------------------------------------------------
__global__ __launch_bounds__(512) void gemm_valu(
    const float* A, const float* __restrict__ W,
    const float* __restrict__ bias, float* C) {
  __shared__ float Bl[16][512];  // [k][n], staged transposed
  __shared__ float Al[64][16];   // [r][k]

  const int tid = threadIdx.x;
  const int rg = tid >> 5;   // 0..15 (4 rows each)
  const int cg = tid & 31;   // 0..31 (16 cols: cg*4 + jj*128)
  const int brow = blockIdx.x * 64;

  float acc[4][16];
#pragma unroll
  for (int i = 0; i < 4; ++i)
#pragma unroll
    for (int j = 0; j < 16; ++j) acc[i][j] = 0.0f;

  for (int kt = 0; kt < 32; ++kt) {
    {
      const float* wp = W + (size_t)tid * 512 + kt * 16;
      float4 w0 = *(const float4*)(wp + 0);
      float4 w1 = *(const float4*)(wp + 4);
      float4 w2 = *(const float4*)(wp + 8);
      float4 w3 = *(const float4*)(wp + 12);
      Bl[0][tid] = w0.x;  Bl[1][tid] = w0.y;  Bl[2][tid] = w0.z;  Bl[3][tid] = w0.w;
      Bl[4][tid] = w1.x;  Bl[5][tid] = w1.y;  Bl[6][tid] = w1.z;  Bl[7][tid] = w1.w;
      Bl[8][tid] = w2.x;  Bl[9][tid] = w2.y;  Bl[10][tid] = w2.z; Bl[11][tid] = w2.w;
      Bl[12][tid] = w3.x; Bl[13][tid] = w3.y; Bl[14][tid] = w3.z; Bl[15][tid] = w3.w;
    }
    {
      const int r = tid >> 3, kk = (tid & 7) * 2;
      const float* ap = A + (size_t)(brow + r) * 512 + kt * 16 + kk;
      Al[r][kk] = ap[0];
      Al[r][kk + 1] = ap[1];
    }
    __syncthreads();
#pragma unroll
    for (int k = 0; k < 16; ++k) {
      const float a0 = Al[rg * 4 + 0][k];
      const float a1 = Al[rg * 4 + 1][k];
      const float a2 = Al[rg * 4 + 2][k];
      const float a3 = Al[rg * 4 + 3][k];
#pragma unroll
      for (int jj = 0; jj < 4; ++jj) {
        float4 b = *(const float4*)&Bl[k][cg * 4 + jj * 128];
        acc[0][jj * 4 + 0] += a0 * b.x; acc[0][jj * 4 + 1] += a0 * b.y;
        acc[0][jj * 4 + 2] += a0 * b.z; acc[0][jj * 4 + 3] += a0 * b.w;
        acc[1][jj * 4 + 0] += a1 * b.x; acc[1][jj * 4 + 1] += a1 * b.y;
        acc[1][jj * 4 + 2] += a1 * b.z; acc[1][jj * 4 + 3] += a1 * b.w;
        acc[2][jj * 4 + 0] += a2 * b.x; acc[2][jj * 4 + 1] += a2 * b.y;
        acc[2][jj * 4 + 2] += a2 * b.z; acc[2][jj * 4 + 3] += a2 * b.w;
        acc[3][jj * 4 + 0] += a3 * b.x; acc[3][jj * 4 + 1] += a3 * b.y;
        acc[3][jj * 4 + 2] += a3 * b.z; acc[3][jj * 4 + 3] += a3 * b.w;
      }
    }
    __syncthreads();
  }

#pragma unroll
  for (int i = 0; i < 4; ++i) {
    const int row = brow + rg * 4 + i;
#pragma unroll
    for (int jj = 0; jj < 4; ++jj) {
      const int c0 = cg * 4 + jj * 128;
      float4 o;
      o.x = acc[i][jj * 4 + 0] + bias[c0 + 0];
      o.y = acc[i][jj * 4 + 1] + bias[c0 + 1];
      o.z = acc[i][jj * 4 + 2] + bias[c0 + 2];
      o.w = acc[i][jj * 4 + 3] + bias[c0 + 3];
      *(float4*)&C[(size_t)row * 512 + c0] = o;
    }
  }
}

// ---------------------------------------------------------------------------
// Scan (r12 EXACT, hardware-proven ~297 µs): prefetch depth 8, one wave per
// batch row, h in fp32 regs, LN via dual shfl_xor butterfly, relu6,
// statically-indexed ring (rule #20). In-place safe.
// ---------------------------------------------------------------------------
__global__ __launch_bounds__(64) void scan_ln_relu6(
    const float* lin, const float* __restrict__ rec,
    const float* __restrict__ gam, const float* __restrict__ bet,
    float* y, float* __restrict__ hlast) {
  const int b = blockIdx.x;
  const int lane = threadIdx.x;
  const int e0 = lane * 8;

  float rf[8], gf[8], bp[8], h[8];
#pragma unroll
  for (int i = 0; i < 8; ++i) {
    rf[i] = rec[e0 + i];
    gf[i] = gam[e0 + i];
    bp[i] = bet[e0 + i];
    h[i] = 0.0f;
  }

  const size_t BH = (size_t)B_DIM * H_DIM;
  const size_t base = (size_t)b * H_DIM + e0;

  float4 pa[8], pb[8];  // prefetch ring: row s0+k held in pa[k]/pb[k]
#pragma unroll
  for (int k = 0; k < 8; ++k) {
    pa[k] = *(const float4*)&lin[base + (size_t)k * BH];
    pb[k] = *(const float4*)&lin[base + (size_t)k * BH + 4];
  }

  for (int s0 = 0; s0 < S_LEN; s0 += 8) {
#pragma unroll
    for (int k = 0; k < 8; ++k) {   // k compile-time after unroll
      const int s = s0 + k;
      float hv[8];
      hv[0] = pa[k].x + rf[0] * h[0]; hv[1] = pa[k].y + rf[1] * h[1];
      hv[2] = pa[k].z + rf[2] * h[2]; hv[3] = pa[k].w + rf[3] * h[3];
      hv[4] = pb[k].x + rf[4] * h[4]; hv[5] = pb[k].y + rf[5] * h[5];
      hv[6] = pb[k].z + rf[6] * h[6]; hv[7] = pb[k].w + rf[7] * h[7];
      if (s + 8 < S_LEN) {  // issue prefetch for s+8 (consumed 8 steps later)
        pa[k] = *(const float4*)&lin[base + (size_t)(s + 8) * BH];
        pb[k] = *(const float4*)&lin[base + (size_t)(s + 8) * BH + 4];
      }
      float s1 = 0.0f, s2 = 0.0f;
#pragma unroll
      for (int i = 0; i < 8; ++i) {
        s1 += hv[i];
        s2 += hv[i] * hv[i];
      }
#pragma unroll
      for (int off = 32; off >= 1; off >>= 1) {
        s1 += __shfl_xor(s1, off);
        s2 += __shfl_xor(s2, off);
      }
      const float mu = s1 * (1.0f / 512.0f);
      const float var = s2 * (1.0f / 512.0f) - mu * mu;  // biased variance
      const float rs = rsqrtf(var + 1e-6f);
      float4 o0, o1;
      float v;
      v = (hv[0] - mu) * rs * gf[0] + bp[0]; v = fminf(fmaxf(v, 0.0f), 6.0f); h[0] = v; o0.x = v;
      v = (hv[1] - mu) * rs * gf[1] + bp[1]; v = fminf(fmaxf(v, 0.0f), 6.0f); h[1] = v; o0.y = v;
      v = (hv[2] - mu) * rs * gf[2] + bp[2]; v = fminf(fmaxf(v, 0.0f), 6.0f); h[2] = v; o0.z = v;
      v = (hv[3] - mu) * rs * gf[3] + bp[3]; v = fminf(fmaxf(v, 0.0f), 6.0f); h[3] = v; o0.w = v;
      v = (hv[4] - mu) * rs * gf[4] + bp[4]; v = fminf(fmaxf(v, 0.0f), 6.0f); h[4] = v; o1.x = v;
      v = (hv[5] - mu) * rs * gf[5] + bp[5]; v = fminf(fmaxf(v, 0.0f), 6.0f); h[5] = v; o1.y = v;
      v = (hv[6] - mu) * rs * gf[6] + bp[6]; v = fminf(fmaxf(v, 0.0f), 6.0f); h[6] = v; o1.z = v;
      v = (hv[7] - mu) * rs * gf[7] + bp[7]; v = fminf(fmaxf(v, 0.0f), 6.0f); h[7] = v; o1.w = v;
      float* yp = y + base + (size_t)s * BH;
      *(float4*)yp = o0;
      *(float4*)(yp + 4) = o1;
    }
  }

  float* hp = hlast + b * 1024 + e0;
  float4 h0; h0.x = h[0]; h0.y = h[1]; h0.z = h[2]; h0.w = h[3];
  float4 h1; h1.x = h[4]; h1.y = h[5]; h1.z = h[6]; h1.w = h[7];
  *(float4*)hp = h0;
  *(float4*)(hp + 4) = h1;
}

extern "C" void kernel_launch(void* const* d_in, const int* in_sizes, int n_in,
                              void* d_out, int out_size, void* d_ws, size_t ws_size,
                              hipStream_t stream) {
  const float* x   = (const float*)d_in[0];
  const float* W0  = (const float*)d_in[1];
  const float* b0  = (const float*)d_in[2];
  const float* r0  = (const float*)d_in[3];
  const float* g0  = (const float*)d_in[4];
  const float* be0 = (const float*)d_in[5];
  const float* W1  = (const float*)d_in[6];
  const float* b1  = (const float*)d_in[7];
  const float* r1  = (const float*)d_in[8];
  const float* g1  = (const float*)d_in[9];
  const float* be1 = (const float*)d_in[10];

  float* out = (float*)d_out;
  float* R   = out;              // y-region: lin0 -> y0 -> lin1 -> y, in place
  float* hl0 = out + Y_SZ;       // hiddens flat: out[Y_SZ + b*1024 + l*512 + h]
  float* hl1 = out + Y_SZ + 512;
  (void)d_ws; (void)ws_size; (void)in_sizes; (void)n_in; (void)out_size;

  // layer 0
  gemm_valu<<<1024, 512, 0, stream>>>(x, W0, b0, R);
  scan_ln_relu6<<<64, 64, 0, stream>>>(R, r0, g0, be0, R, hl0);
  // layer 1 (reads y0 from R, writes lin1 over R; in-place-safe by design)
  gemm_valu<<<1024, 512, 0, stream>>>(R, W1, b1, R);
  scan_ln_relu6<<<64, 64, 0, stream>>>(R, r1, g1, be1, R, hl1);
}

// Round 14
// 1336.809 us; speedup vs baseline: 1.2986x; 1.2437x over previous
//
#include <hip/hip_runtime.h>

#define S_LEN 1024
#define B_DIM 64
#define H_DIM 512
#define Y_SZ ((size_t)S_LEN * B_DIM * H_DIM)   // 33,554,432 elements

// ---------------------------------------------------------------------------
// GEMM (r11/r13 EXACT, hardware-proven 492 µs, 64 VGPR -> 8 waves/SIMD).
// C[m,n] = sum_k A[m,k]*W[n,k] + bias[n]. Pure VALU fp32. Block owns 64 rows
// exclusively; all C stores deferred past the last staging barrier ->
// in-place safe (C may alias A). DO NOT add register pressure (r12: 68 VGPR
// halved occupancy -> 570 µs).
// ---------------------------------------------------------------------------
__global__ __launch_bounds__(512) void gemm_valu(
    const float* A, const float* __restrict__ W,
    const float* __restrict__ bias, float* C) {
  __shared__ float Bl[16][512];  // [k][n], staged transposed
  __shared__ float Al[64][16];   // [r][k]

  const int tid = threadIdx.x;
  const int rg = tid >> 5;   // 0..15 (4 rows each)
  const int cg = tid & 31;   // 0..31 (16 cols: cg*4 + jj*128)
  const int brow = blockIdx.x * 64;

  float acc[4][16];
#pragma unroll
  for (int i = 0; i < 4; ++i)
#pragma unroll
    for (int j = 0; j < 16; ++j) acc[i][j] = 0.0f;

  for (int kt = 0; kt < 32; ++kt) {
    {
      const float* wp = W + (size_t)tid * 512 + kt * 16;
      float4 w0 = *(const float4*)(wp + 0);
      float4 w1 = *(const float4*)(wp + 4);
      float4 w2 = *(const float4*)(wp + 8);
      float4 w3 = *(const float4*)(wp + 12);
      Bl[0][tid] = w0.x;  Bl[1][tid] = w0.y;  Bl[2][tid] = w0.z;  Bl[3][tid] = w0.w;
      Bl[4][tid] = w1.x;  Bl[5][tid] = w1.y;  Bl[6][tid] = w1.z;  Bl[7][tid] = w1.w;
      Bl[8][tid] = w2.x;  Bl[9][tid] = w2.y;  Bl[10][tid] = w2.z; Bl[11][tid] = w2.w;
      Bl[12][tid] = w3.x; Bl[13][tid] = w3.y; Bl[14][tid] = w3.z; Bl[15][tid] = w3.w;
    }
    {
      const int r = tid >> 3, kk = (tid & 7) * 2;
      const float* ap = A + (size_t)(brow + r) * 512 + kt * 16 + kk;
      Al[r][kk] = ap[0];
      Al[r][kk + 1] = ap[1];
    }
    __syncthreads();
#pragma unroll
    for (int k = 0; k < 16; ++k) {
      const float a0 = Al[rg * 4 + 0][k];
      const float a1 = Al[rg * 4 + 1][k];
      const float a2 = Al[rg * 4 + 2][k];
      const float a3 = Al[rg * 4 + 3][k];
#pragma unroll
      for (int jj = 0; jj < 4; ++jj) {
        float4 b = *(const float4*)&Bl[k][cg * 4 + jj * 128];
        acc[0][jj * 4 + 0] += a0 * b.x; acc[0][jj * 4 + 1] += a0 * b.y;
        acc[0][jj * 4 + 2] += a0 * b.z; acc[0][jj * 4 + 3] += a0 * b.w;
        acc[1][jj * 4 + 0] += a1 * b.x; acc[1][jj * 4 + 1] += a1 * b.y;
        acc[1][jj * 4 + 2] += a1 * b.z; acc[1][jj * 4 + 3] += a1 * b.w;
        acc[2][jj * 4 + 0] += a2 * b.x; acc[2][jj * 4 + 1] += a2 * b.y;
        acc[2][jj * 4 + 2] += a2 * b.z; acc[2][jj * 4 + 3] += a2 * b.w;
        acc[3][jj * 4 + 0] += a3 * b.x; acc[3][jj * 4 + 1] += a3 * b.y;
        acc[3][jj * 4 + 2] += a3 * b.z; acc[3][jj * 4 + 3] += a3 * b.w;
      }
    }
    __syncthreads();
  }

#pragma unroll
  for (int i = 0; i < 4; ++i) {
    const int row = brow + rg * 4 + i;
#pragma unroll
    for (int jj = 0; jj < 4; ++jj) {
      const int c0 = cg * 4 + jj * 128;
      float4 o;
      o.x = acc[i][jj * 4 + 0] + bias[c0 + 0];
      o.y = acc[i][jj * 4 + 1] + bias[c0 + 1];
      o.z = acc[i][jj * 4 + 2] + bias[c0 + 2];
      o.w = acc[i][jj * 4 + 3] + bias[c0 + 3];
      *(float4*)&C[(size_t)row * 512 + c0] = o;
    }
  }
}

// ---------------------------------------------------------------------------
// DPP wave64 sum-reduce helpers (gfx9 lineage; VALU-latency cross-lane adds
// instead of ds_bpermute). After the bcast31 step the full 64-lane sum is in
// lanes 48-63; readlane(63) broadcasts it as a wave-uniform value.
// ---------------------------------------------------------------------------
__device__ static inline float dpp_add_step(float v, const int ctrl) {
  int perm;
  switch (ctrl) {  // ctrl is compile-time constant at each call site
    case 0xB1:  perm = __builtin_amdgcn_update_dpp(0, __builtin_bit_cast(int, v), 0xB1,  0xF, 0xF, true); break;
    case 0x4E:  perm = __builtin_amdgcn_update_dpp(0, __builtin_bit_cast(int, v), 0x4E,  0xF, 0xF, true); break;
    case 0x141: perm = __builtin_amdgcn_update_dpp(0, __builtin_bit_cast(int, v), 0x141, 0xF, 0xF, true); break;
    case 0x140: perm = __builtin_amdgcn_update_dpp(0, __builtin_bit_cast(int, v), 0x140, 0xF, 0xF, true); break;
    case 0x142: perm = __builtin_amdgcn_update_dpp(0, __builtin_bit_cast(int, v), 0x142, 0xF, 0xF, true); break;
    default:    perm = __builtin_amdgcn_update_dpp(0, __builtin_bit_cast(int, v), 0x143, 0xF, 0xF, true); break;
  }
  return v + __builtin_bit_cast(float, perm);
}

// ---------------------------------------------------------------------------
// Scan: r13 structure (depth-8 prefetch ring, one wave per batch row, h in
// fp32 regs, relu6, in-place safe) with the ONE change: the dual shfl_xor
// butterfly (12 dependent ds_bpermute, ~400+ cyc) replaced by interleaved
// DPP reductions (12 VALU-DPP adds + 2 readlane).
// ---------------------------------------------------------------------------
__global__ __launch_bounds__(64) void scan_ln_relu6(
    const float* lin, const float* __restrict__ rec,
    const float* __restrict__ gam, const float* __restrict__ bet,
    float* y, float* __restrict__ hlast) {
  const int b = blockIdx.x;
  const int lane = threadIdx.x;
  const int e0 = lane * 8;

  float rf[8], gf[8], bp[8], h[8];
#pragma unroll
  for (int i = 0; i < 8; ++i) {
    rf[i] = rec[e0 + i];
    gf[i] = gam[e0 + i];
    bp[i] = bet[e0 + i];
    h[i] = 0.0f;
  }

  const size_t BH = (size_t)B_DIM * H_DIM;
  const size_t base = (size_t)b * H_DIM + e0;

  float4 pa[8], pb[8];  // prefetch ring: row s0+k held in pa[k]/pb[k]
#pragma unroll
  for (int k = 0; k < 8; ++k) {
    pa[k] = *(const float4*)&lin[base + (size_t)k * BH];
    pb[k] = *(const float4*)&lin[base + (size_t)k * BH + 4];
  }

  for (int s0 = 0; s0 < S_LEN; s0 += 8) {
#pragma unroll
    for (int k = 0; k < 8; ++k) {   // k compile-time after unroll
      const int s = s0 + k;
      float hv[8];
      hv[0] = pa[k].x + rf[0] * h[0]; hv[1] = pa[k].y + rf[1] * h[1];
      hv[2] = pa[k].z + rf[2] * h[2]; hv[3] = pa[k].w + rf[3] * h[3];
      hv[4] = pb[k].x + rf[4] * h[4]; hv[5] = pb[k].y + rf[5] * h[5];
      hv[6] = pb[k].z + rf[6] * h[6]; hv[7] = pb[k].w + rf[7] * h[7];
      if (s + 8 < S_LEN) {  // issue prefetch for s+8 (consumed 8 steps later)
        pa[k] = *(const float4*)&lin[base + (size_t)(s + 8) * BH];
        pb[k] = *(const float4*)&lin[base + (size_t)(s + 8) * BH + 4];
      }
      float s1 = 0.0f, s2 = 0.0f;
#pragma unroll
      for (int i = 0; i < 8; ++i) {
        s1 += hv[i];
        s2 += hv[i] * hv[i];
      }
      // --- interleaved DPP butterfly: full 64-lane sums of s1, s2 ---
      s1 = dpp_add_step(s1, 0xB1);  s2 = dpp_add_step(s2, 0xB1);   // quad xor1
      s1 = dpp_add_step(s1, 0x4E);  s2 = dpp_add_step(s2, 0x4E);   // quad xor2
      s1 = dpp_add_step(s1, 0x141); s2 = dpp_add_step(s2, 0x141);  // half_mirror
      s1 = dpp_add_step(s1, 0x140); s2 = dpp_add_step(s2, 0x140);  // row_mirror
      s1 = dpp_add_step(s1, 0x142); s2 = dpp_add_step(s2, 0x142);  // bcast15
      s1 = dpp_add_step(s1, 0x143); s2 = dpp_add_step(s2, 0x143);  // bcast31
      const float S1 = __builtin_bit_cast(float,
          __builtin_amdgcn_readlane(__builtin_bit_cast(int, s1), 63));
      const float S2 = __builtin_bit_cast(float,
          __builtin_amdgcn_readlane(__builtin_bit_cast(int, s2), 63));
      const float mu = S1 * (1.0f / 512.0f);
      const float var = S2 * (1.0f / 512.0f) - mu * mu;  // biased variance
      const float rs = rsqrtf(var + 1e-6f);
      float4 o0, o1;
      float v;
      v = (hv[0] - mu) * rs * gf[0] + bp[0]; v = fminf(fmaxf(v, 0.0f), 6.0f); h[0] = v; o0.x = v;
      v = (hv[1] - mu) * rs * gf[1] + bp[1]; v = fminf(fmaxf(v, 0.0f), 6.0f); h[1] = v; o0.y = v;
      v = (hv[2] - mu) * rs * gf[2] + bp[2]; v = fminf(fmaxf(v, 0.0f), 6.0f); h[2] = v; o0.z = v;
      v = (hv[3] - mu) * rs * gf[3] + bp[3]; v = fminf(fmaxf(v, 0.0f), 6.0f); h[3] = v; o0.w = v;
      v = (hv[4] - mu) * rs * gf[4] + bp[4]; v = fminf(fmaxf(v, 0.0f), 6.0f); h[4] = v; o1.x = v;
      v = (hv[5] - mu) * rs * gf[5] + bp[5]; v = fminf(fmaxf(v, 0.0f), 6.0f); h[5] = v; o1.y = v;
      v = (hv[6] - mu) * rs * gf[6] + bp[6]; v = fminf(fmaxf(v, 0.0f), 6.0f); h[6] = v; o1.z = v;
      v = (hv[7] - mu) * rs * gf[7] + bp[7]; v = fminf(fmaxf(v, 0.0f), 6.0f); h[7] = v; o1.w = v;
      float* yp = y + base + (size_t)s * BH;
      *(float4*)yp = o0;
      *(float4*)(yp + 4) = o1;
    }
  }

  float* hp = hlast + b * 1024 + e0;
  float4 h0; h0.x = h[0]; h0.y = h[1]; h0.z = h[2]; h0.w = h[3];
  float4 h1; h1.x = h[4]; h1.y = h[5]; h1.z = h[6]; h1.w = h[7];
  *(float4*)hp = h0;
  *(float4*)(hp + 4) = h1;
}

extern "C" void kernel_launch(void* const* d_in, const int* in_sizes, int n_in,
                              void* d_out, int out_size, void* d_ws, size_t ws_size,
                              hipStream_t stream) {
  const float* x   = (const float*)d_in[0];
  const float* W0  = (const float*)d_in[1];
  const float* b0  = (const float*)d_in[2];
  const float* r0  = (const float*)d_in[3];
  const float* g0  = (const float*)d_in[4];
  const float* be0 = (const float*)d_in[5];
  const float* W1  = (const float*)d_in[6];
  const float* b1  = (const float*)d_in[7];
  const float* r1  = (const float*)d_in[8];
  const float* g1  = (const float*)d_in[9];
  const float* be1 = (const float*)d_in[10];

  float* out = (float*)d_out;
  float* R   = out;              // y-region: lin0 -> y0 -> lin1 -> y, in place
  float* hl0 = out + Y_SZ;       // hiddens flat: out[Y_SZ + b*1024 + l*512 + h]
  float* hl1 = out + Y_SZ + 512;
  (void)d_ws; (void)ws_size; (void)in_sizes; (void)n_in; (void)out_size;

  // layer 0
  gemm_valu<<<1024, 512, 0, stream>>>(x, W0, b0, R);
  scan_ln_relu6<<<64, 64, 0, stream>>>(R, r0, g0, be0, R, hl0);
  // layer 1 (reads y0 from R, writes lin1 over R; in-place-safe by design)
  gemm_valu<<<1024, 512, 0, stream>>>(R, W1, b1, R);
  scan_ln_relu6<<<64, 64, 0, stream>>>(R, r1, g1, be1, R, hl1);
}